// Round 3
// baseline (434.549 us; speedup 1.0000x reference)
//
#include <hip/hip_runtime.h>

// Fused attention fwd: R = softmax(Q K^T / sqrt(D)) V, plus attn weights P.
// B=16, LQ=LK=2048, D=128, fp32 in/out.
//
// Round 6. r5 analysis: LDS pipe ~85% occupied (per-iter accounting matches
// MfmaUtil 10 / VALU 15 / HBM 20 all-low signature) -> cut LDS traffic.
//  1) Pass-1 remap: wave = 32 keys x all-64-q (was q-half x key-half, where
//     wm-pair waves read IDENTICAL kf frags). kf reads halve (16->8 b128 per
//     wave-iter); aq both halves held in regs (64 VGPR, free at 2 blocks/CU);
//     two independent MFMA chains (c0,c1) -> better ILP; two scalar psums.
//  2) V staging: 16x scattered 4B writes (main bank-conflict source) -> 4x
//     b128 writes. Lane owns d=(2*lane, 2*lane+1), k-octets (wave, wave+4):
//     16 coalesced 8B global loads (512B/instr rows), pack bf16x8 along k,
//     write 16B chunks into the same XOR-swizzled Vt blocks.
// Kept from r5: swapped QK^T (per-lane scalar softmax), lgkm-only barriers,
// coalesced K staging, quad P store (full 64B lines), nontemporal stores.

#define NB  16
#define SLQ 2048
#define SLK 2048
#define DH  128
#define BQ  64
#define BK  64

typedef __bf16 bf16;
typedef bf16  bf16x8 __attribute__((ext_vector_type(8)));
typedef bf16  bf16x4 __attribute__((ext_vector_type(4)));
typedef float f32x2  __attribute__((ext_vector_type(2)));
typedef float f32x4  __attribute__((ext_vector_type(4)));
typedef float f32x16 __attribute__((ext_vector_type(16)));

#define SCALE 0.088388347648318447f  // 1/sqrt(128)

__device__ __forceinline__ f32x16 mfma32(bf16x8 a, bf16x8 b, f32x16 c) {
    return __builtin_amdgcn_mfma_f32_32x32x16_bf16(a, b, c, 0, 0, 0);
}

__device__ __forceinline__ bf16x8 cvt8(f32x4 v0, f32x4 v1) {
    bf16x8 r;
    r[0] = (bf16)v0[0]; r[1] = (bf16)v0[1]; r[2] = (bf16)v0[2]; r[3] = (bf16)v0[3];
    r[4] = (bf16)v1[0]; r[5] = (bf16)v1[1]; r[6] = (bf16)v1[2]; r[7] = (bf16)v1[3];
    return r;
}

__device__ __forceinline__ bf16x8 cvt8s(f32x4 v0, f32x4 v1, float s) {
    bf16x8 r;
    r[0] = (bf16)(v0[0] * s); r[1] = (bf16)(v0[1] * s);
    r[2] = (bf16)(v0[2] * s); r[3] = (bf16)(v0[3] * s);
    r[4] = (bf16)(v1[0] * s); r[5] = (bf16)(v1[1] * s);
    r[6] = (bf16)(v1[2] * s); r[7] = (bf16)(v1[3] * s);
    return r;
}

// Workgroup barrier waiting only on LDS ops (lgkmcnt), NOT vmcnt -- P stores
// and prefetch loads stream across it; compiler inserts counted vmcnt for
// register consumption.
__device__ __forceinline__ void barrier_lgkm() {
    asm volatile("s_waitcnt lgkmcnt(0)" ::: "memory");
    __builtin_amdgcn_s_barrier();
    asm volatile("" ::: "memory");
}

__global__ __launch_bounds__(256, 2)
void attn_fused(const float* __restrict__ Q, const float* __restrict__ K,
                const float* __restrict__ V, float* __restrict__ Rout,
                float* __restrict__ Pout) {
    const int b = blockIdx.x, qt = blockIdx.y;   // batch-major: XCD = b % 8
    const int tid  = threadIdx.x;
    const int wave = tid >> 6, lane = tid & 63;
    const int n31 = lane & 31, h = lane >> 5;
    const int wm = wave & 1, wn = wave >> 1;     // pass-2 tiling only

    // LDS: pass2 Ks[64][136] | Vt[128][72] | Ps[64][72] ; pass1 aliases
    // Ks1[128][136] (34816 B) over Ks+Vt. rsum[4][64] tail.
    __shared__ __align__(16) char smem[45056 + 1024];
    bf16 (*Ks)[136]  = (bf16(*)[136])smem;
    bf16 (*Ks1)[136] = (bf16(*)[136])smem;
    bf16 (*Vt)[72]   = (bf16(*)[72])(smem + 17408);
    bf16 (*Ps)[72]   = (bf16(*)[72])(smem + 35840);
    float* rsum      = (float*)(smem + 45056);   // [wave][64]

    const float* Qb = Q + ((size_t)b * SLQ + qt * BQ) * DH;
    const float* Kb = K + (size_t)b * SLK * DH;
    const float* Vb = V + (size_t)b * SLK * DH;
    float* Rb = Rout + ((size_t)b * SLQ + qt * BQ) * DH;
    float* Pb = Pout + ((size_t)b * SLQ + qt * BQ) * SLK;

    // Q B-frags for BOTH q-halves (pass 1 uses both; pass 2 selects wm half).
    // aqm[kk] per lane = Q[m*32+n31][kk*16+8h .. +7], scale folded.
    bf16x8 aq0[8], aq1[8];
    {
        const float* qp0 = Qb + (size_t)n31 * DH + h * 8;
        const float* qp1 = qp0 + 32 * DH;
#pragma unroll
        for (int kk = 0; kk < 8; ++kk) {
            aq0[kk] = cvt8s(*(const f32x4*)(qp0 + kk * 16),
                            *(const f32x4*)(qp0 + kk * 16 + 4), SCALE);
            aq1[kk] = cvt8s(*(const f32x4*)(qp1 + kk * 16),
                            *(const f32x4*)(qp1 + kk * 16 + 4), SCALE);
        }
    }

    // ---------------- pass 1: row sums (BK=128, 16 tiles) ----------------
    // Wave w owns keys w*32..w*32+31 of each tile, ALL 64 q (no duplicated
    // kf reads across waves). c0/c1 = S^T for q-halves 0/1 (col = q).
    float ps0 = 0.f, ps1 = 0.f;
    {
        f32x4 kreg[16];
#pragma unroll
        for (int i = 0; i < 8; ++i) {
            int f = tid + i * 256, row = f >> 4, g = f & 15;
            const float* kp = Kb + (size_t)row * DH + g * 8;
            kreg[2 * i]     = *(const f32x4*)kp;
            kreg[2 * i + 1] = *(const f32x4*)(kp + 4);
        }
        for (int kt = 0; kt < 16; ++kt) {
            barrier_lgkm();   // prior-iter frag reads done
#pragma unroll
            for (int i = 0; i < 8; ++i) {
                int f = tid + i * 256, row = f >> 4, g = f & 15;
                *(bf16x8*)&Ks1[row][g * 8] = cvt8(kreg[2 * i], kreg[2 * i + 1]);
            }
            barrier_lgkm();   // staging visible
            if (kt + 1 < 16) {
#pragma unroll
                for (int i = 0; i < 8; ++i) {
                    int f = tid + i * 256, row = f >> 4, g = f & 15;
                    const float* kp = Kb + (size_t)((kt + 1) * 128 + row) * DH + g * 8;
                    kreg[2 * i]     = *(const f32x4*)kp;
                    kreg[2 * i + 1] = *(const f32x4*)(kp + 4);
                }
            }
            f32x16 c0 = (f32x16)0.0f, c1 = (f32x16)0.0f;
#pragma unroll
            for (int kk = 0; kk < 8; ++kk) {
                bf16x8 kf = *(const bf16x8*)&Ks1[wave * 32 + n31][kk * 16 + h * 8];
                c0 = mfma32(kf, aq0[kk], c0);
                c1 = mfma32(kf, aq1[kk], c1);
            }
#pragma unroll
            for (int r = 0; r < 16; ++r) { ps0 += __expf(c0[r]); ps1 += __expf(c1[r]); }
        }
    }

    // prefetch pass-2 tile 0 (K/V re-reads are L2-hot); overlaps reduction
    const int dv = 2 * lane;          // V-stage: this lane owns d = dv, dv+1
    f32x4 kreg2[8];
    f32x2 vr0[8], vr1[8];             // [j] = V[k0+j][dv..dv+1], k0 = 8*wave (+32)
#pragma unroll
    for (int i = 0; i < 4; ++i) {
        int f = tid + i * 256, row = f >> 4, g = f & 15;
        const float* kp = Kb + (size_t)row * DH + g * 8;
        kreg2[2 * i]     = *(const f32x4*)kp;
        kreg2[2 * i + 1] = *(const f32x4*)(kp + 4);
    }
#pragma unroll
    for (int j = 0; j < 8; ++j) {
        vr0[j] = *(const f32x2*)(Vb + (size_t)(8 * wave + j) * DH + dv);
        vr1[j] = *(const f32x2*)(Vb + (size_t)(8 * wave + 32 + j) * DH + dv);
    }

    // merge h halves (shfl), then the 4 wave key-groups via LDS
    ps0 += __shfl_xor(ps0, 32);
    ps1 += __shfl_xor(ps1, 32);
    if (lane < 32) {
        rsum[wave * 64 + n31]      = ps0;
        rsum[wave * 64 + 32 + n31] = ps1;
    }
    barrier_lgkm();
    const int qrow = wm * 32 + n31;
    const float rinv = 1.0f / (rsum[qrow] + rsum[64 + qrow] +
                               rsum[128 + qrow] + rsum[192 + qrow]);

    // pass-2 Q frags: select this wave's q-half (wave-uniform cndmask)
    bf16x8 aqp[8];
#pragma unroll
    for (int kk = 0; kk < 8; ++kk) aqp[kk] = wm ? aq1[kk] : aq0[kk];

    f32x16 racc[2];
    racc[0] = (f32x16)0.0f;
    racc[1] = (f32x16)0.0f;

    // ---------------- pass 2: P store + PV (BK=64, 32 tiles) ----------------
    for (int kt = 0; kt < 32; ++kt) {
        barrier_lgkm();   // A: prev-iter PV/P-store LDS reads done
        // stage K tile [k][d] (coalesced regs -> LDS)
#pragma unroll
        for (int i = 0; i < 4; ++i) {
            int f = tid + i * 256, row = f >> 4, g = f & 15;
            *(bf16x8*)&Ks[row][g * 8] = cvt8(kreg2[2 * i], kreg2[2 * i + 1]);
        }
        // stage V^T [d][k]: k-contiguous b128 writes into XOR-swizzled blocks
        // pb = kblock ^ ((d>>3)&7); dv even so dv,dv+1 share (d>>3).
        {
            int sw = (dv >> 3) & 7;
            bf16x8 w0, w1;
#pragma unroll
            for (int j = 0; j < 8; ++j) { w0[j] = (bf16)vr0[j][0]; w1[j] = (bf16)vr0[j][1]; }
            int pb = wave ^ sw;
            *(bf16x8*)&Vt[dv][pb * 8]     = w0;
            *(bf16x8*)&Vt[dv + 1][pb * 8] = w1;
#pragma unroll
            for (int j = 0; j < 8; ++j) { w0[j] = (bf16)vr1[j][0]; w1[j] = (bf16)vr1[j][1]; }
            pb = (wave + 4) ^ sw;
            *(bf16x8*)&Vt[dv][pb * 8]     = w0;
            *(bf16x8*)&Vt[dv + 1][pb * 8] = w1;
        }
        barrier_lgkm();   // B: Ks/Vt visible

        // QK^T swapped: c = S^T sub-tile (keys wn*32.., q-col = lane)
        f32x16 c = (f32x16)0.0f;
#pragma unroll
        for (int kk = 0; kk < 8; ++kk) {
            bf16x8 kf = *(const bf16x8*)&Ks[wn * 32 + n31][kk * 16 + h * 8];
            c = mfma32(kf, aqp[kk], c);
        }
        // softmax -> Ps, 4x b64 writes (reg r -> key wn*32+(r&3)+8*(r>>2)+4h)
#pragma unroll
        for (int g = 0; g < 4; ++g) {
            bf16x4 pw;
            pw[0] = (bf16)(__expf(c[4 * g + 0]) * rinv);
            pw[1] = (bf16)(__expf(c[4 * g + 1]) * rinv);
            pw[2] = (bf16)(__expf(c[4 * g + 2]) * rinv);
            pw[3] = (bf16)(__expf(c[4 * g + 3]) * rinv);
            *(bf16x4*)&Ps[qrow][wn * 32 + 4 * h + 8 * g] = pw;
        }

        // prefetch next tile (issued BEFORE this iter's P stores, so the
        // next-iter staging wait is a counted vmcnt that skips the stores)
        if (kt + 1 < 32) {
#pragma unroll
            for (int i = 0; i < 4; ++i) {
                int f = tid + i * 256, row = f >> 4, g = f & 15;
                const float* kp = Kb + (size_t)((kt + 1) * 64 + row) * DH + g * 8;
                kreg2[2 * i]     = *(const f32x4*)kp;
                kreg2[2 * i + 1] = *(const f32x4*)(kp + 4);
            }
            const float* vb = Vb + (size_t)(kt + 1) * 64 * DH + dv;
#pragma unroll
            for (int j = 0; j < 8; ++j) {
                vr0[j] = *(const f32x2*)(vb + (size_t)(8 * wave + j) * DH);
                vr1[j] = *(const f32x2*)(vb + (size_t)(8 * wave + 32 + j) * DH);
            }
        }
        barrier_lgkm();   // C: Ps visible (cross-wave for P store + PV A-frags)

        // P global store: quad pattern, each instr covers full 64B lines
        {
            int prow = tid >> 2, pc = tid & 3;
            float* dst = Pb + (size_t)prow * SLK + kt * 64;
#pragma unroll
            for (int u = 0; u < 4; ++u) {
                bf16x4 pv = *(const bf16x4*)&Ps[prow][u * 16 + pc * 4];
                f32x4 o;
                o[0] = (float)pv[0]; o[1] = (float)pv[1];
                o[2] = (float)pv[2]; o[3] = (float)pv[3];
                __builtin_nontemporal_store(o, (f32x4*)(dst + u * 16 + pc * 4));
            }
        }

        // PV: R rows wm*32+.., d-cols wn*64 + t*32 + n31
#pragma unroll
        for (int kk = 0; kk < 4; ++kk) {
            bf16x8 ap = *(const bf16x8*)&Ps[qrow][kk * 16 + 8 * h];
#pragma unroll
            for (int t = 0; t < 2; ++t) {
                int d = wn * 64 + t * 32 + n31;
                int pb = (2 * kk + h) ^ ((d >> 3) & 7);
                bf16x8 bv = *(const bf16x8*)&Vt[d][pb * 8];
                racc[t] = mfma32(ap, bv, racc[t]);
            }
        }
    }

    // epilogue: R store (C layout: col = wn*64+t*32+n31, row per reg map)
#pragma unroll
    for (int t = 0; t < 2; ++t)
#pragma unroll
        for (int r = 0; r < 16; ++r) {
            int row = wm * 32 + (r & 3) + 8 * (r >> 2) + 4 * h;
            int d   = wn * 64 + t * 32 + n31;
            __builtin_nontemporal_store(racc[t][r], &Rb[(size_t)row * DH + d]);
        }
}

extern "C" void kernel_launch(void* const* d_in, const int* in_sizes, int n_in,
                              void* d_out, int out_size, void* d_ws, size_t ws_size,
                              hipStream_t stream) {
    (void)in_sizes; (void)n_in; (void)out_size; (void)d_ws; (void)ws_size;
    const float* Q = (const float*)d_in[0];
    const float* K = (const float*)d_in[1];
    const float* V = (const float*)d_in[2];
    float* R = (float*)d_out;
    float* P = (float*)d_out + (size_t)NB * SLQ * DH;

    dim3 grid(NB, SLQ / BQ);  // 512 blocks, batch-major for XCD L2 locality
    attn_fused<<<grid, 256, 0, stream>>>(Q, K, V, R, P);
}